// Round 6
// baseline (294.802 us; speedup 1.0000x reference)
//
#include <hip/hip_runtime.h>
#include <math.h>

#define CB 512
#define CS 1024
#define CT 50
#define PF 8   // x-prefetch depth / renorm cadence (range-safe: e^(12+48) << fp32 max)

typedef float v2f __attribute__((ext_vector_type(2)));

__global__ void zero_out_kernel(float* out) { out[0] = 0.0f; }

// Compiler-level fence only — same-wave DS ops complete in order on CDNA.
__device__ __forceinline__ void wave_fence() {
    __builtin_amdgcn_wave_barrier();
    asm volatile("" ::: "memory");
}

__device__ __forceinline__ int lane0_bits(float v) {
    return __builtin_amdgcn_readlane(__float_as_int(v), 0);
}

// quad_perm DPP (VALU pipe): 0xB1=xor1, 0x4E=xor2, 0x00/0x55/0xAA/0xFF=bcast quad lane k
template <int CTRL>
__device__ __forceinline__ float qperm(float v) {
    return __int_as_float(__builtin_amdgcn_update_dpp(
        0, __float_as_int(v), CTRL, 0xf, 0xf, false));
}

__global__ __launch_bounds__(128, 1) void crf_scan_kernel(
    const float* __restrict__ scores,    // (B,S,T)
    const int*   __restrict__ tags,      // (B,S)
    const int*   __restrict__ mask,      // (B,S)
    const float* __restrict__ trans,     // (T,T)
    const float* __restrict__ start_tr,  // (T)
    const float* __restrict__ end_tr,    // (T)
    float* __restrict__ out)             // scalar
{
    const int b    = blockIdx.x;
    const int tid  = threadIdx.x;
    const int w    = tid >> 6;           // wave 0 = forward, wave 1 = backward
    const int lane = tid & 63;
    const int g    = lane & 3;           // i-quarter this lane accumulates
    const int m    = lane >> 2;          // quad index: quad owns states 4m..4m+3

    __shared__ __attribute__((aligned(16))) float sTrans[CT * CT];
    __shared__ __attribute__((aligned(16))) float sP2[2][64];
    __shared__ __attribute__((aligned(16))) float sA[64];
    __shared__ __attribute__((aligned(16))) float sB[64];
    __shared__ float sLZ[2], sN[2];

    for (int k = tid; k < CT * CT; k += 128) sTrans[k] = trans[k];
    __syncthreads();

    // E fragments: lane covers i in [16g,16g+16), states s = 4m+c (c<4).
    // fwd: coeff(i,s)=exp(trans[i][s]); bwd: coeff(i,s)=exp(trans[s][i]).
    // Pads (i>=50 or s>=50) are exactly 0 so pad states stay 0 forever.
    v2f EC0[16], EC1[16];
    {
        const int i0 = 16 * g, s0 = 4 * m;
        #pragma unroll
        for (int kk = 0; kk < 16; ++kk) {
            const int i = i0 + kk;
            float e[4] = {0.f, 0.f, 0.f, 0.f};
            if (i < CT) {
                #pragma unroll
                for (int c = 0; c < 4; ++c) {
                    const int s = s0 + c;
                    if (s < CT)
                        e[c] = __expf(w == 0 ? sTrans[i * CT + s]
                                             : sTrans[s * CT + i]);
                }
            }
            EC0[kk] = (v2f){e[0], e[1]};
            EC1[kk] = (v2f){e[2], e[3]};
        }
    }

    // sequence length (prefix mask)
    const int* mrow = mask + (size_t)b * CS;
    int len = 0;
    for (int t = lane; t < CS; t += 64) len += mrow[t];
    #pragma unroll
    for (int off = 32; off; off >>= 1) len += __shfl_xor(len, off);

    const float* srow = scores + (size_t)b * CS * CT;
    const int xl      = (lane < CT) ? lane : 0;
    const float* sx   = srow + xl;

    const int tm    = (len - 1) >> 1;
    const int count = (w == 0) ? tm : ((len >= 2) ? (len - 2 - tm) : 0);
    const int base  = (w == 0) ? 1 : (len - 2);
    const int dir   = (w == 0) ? 1 : -1;

    // Seed: every lane computes its quad's 4 initial states (replicated in-quad).
    // fwd: p0[s]=exp(start[s]+x0[s]); bwd: C[s]=exp(end[s]+x_{len-1}[s]) (or exp(end) if len==1)
    v2f C01, C23;
    {
        float c4[4];
        #pragma unroll
        for (int c = 0; c < 4; ++c) {
            const int s = 4 * m + c;
            if (s < CT) {
                if (w == 0)      c4[c] = __expf(start_tr[s] + srow[s]);
                else if (len >= 2) c4[c] = __expf(end_tr[s] + srow[(size_t)(len - 1) * CT + s]);
                else             c4[c] = __expf(end_tr[s]);
            } else c4[c] = 0.f;
        }
        C01 = (v2f){c4[0], c4[1]};
        C23 = (v2f){c4[2], c4[3]};
    }

    int kexp = 0;
    float scl = 1.0f;
    float* sP = sP2[w];
    const float* sPq = sP + 16 * g;

    // One step. EXJ = per-lane exp(x_t[own state]) (already renorm-scaled if due).
    // write (quad j==0 lanes, b128) -> read 4xb128 -> 8+8 FMA -> butterfly all-reduce
    // -> multiply by quad-gathered ex -> comps replicated in-quad again.
    #define STEP(EXJ)                                                       \
    {                                                                       \
        if ((lane & 3) == 0)                                                \
            *(float4*)&sP[lane] = make_float4(C01.x, C01.y, C23.x, C23.y);  \
        wave_fence();                                                       \
        const float4 p0 = *(const float4*)&sPq[0];                          \
        const float4 p1 = *(const float4*)&sPq[4];                          \
        const float4 p2 = *(const float4*)&sPq[8];                          \
        const float4 p3 = *(const float4*)&sPq[12];                         \
        const float exj = (EXJ);                                            \
        const float e0 = qperm<0x00>(exj), e1 = qperm<0x55>(exj);           \
        const float e2 = qperm<0xAA>(exj), e3 = qperm<0xFF>(exj);           \
        float pv[16] = {p0.x,p0.y,p0.z,p0.w, p1.x,p1.y,p1.z,p1.w,           \
                        p2.x,p2.y,p2.z,p2.w, p3.x,p3.y,p3.z,p3.w};          \
        v2f a0a={0.f,0.f}, a0b={0.f,0.f}, a1a={0.f,0.f}, a1b={0.f,0.f};     \
        _Pragma("unroll")                                                   \
        for (int kk = 0; kk < 8; ++kk) {                                    \
            const v2f t2 = {pv[kk], pv[kk]};                                \
            a0a = __builtin_elementwise_fma(t2, EC0[kk], a0a);              \
            a1a = __builtin_elementwise_fma(t2, EC1[kk], a1a);              \
        }                                                                   \
        _Pragma("unroll")                                                   \
        for (int kk = 8; kk < 16; ++kk) {                                   \
            const v2f t2 = {pv[kk], pv[kk]};                                \
            a0b = __builtin_elementwise_fma(t2, EC0[kk], a0b);              \
            a1b = __builtin_elementwise_fma(t2, EC1[kk], a1b);              \
        }                                                                   \
        v2f A0 = a0a + a0b, A1 = a1a + a1b;                                 \
        A0.x += qperm<0xB1>(A0.x); A0.y += qperm<0xB1>(A0.y);               \
        A1.x += qperm<0xB1>(A1.x); A1.y += qperm<0xB1>(A1.y);               \
        A0.x += qperm<0x4E>(A0.x); A0.y += qperm<0x4E>(A0.y);               \
        A1.x += qperm<0x4E>(A1.x); A1.y += qperm<0x4E>(A1.y);               \
        C01 = A0 * (v2f){e0, e1};                                           \
        C23 = A1 * (v2f){e2, e3};                                           \
    }

    // Renorm accounting: exponent of lane0's state-0 value; scale folded into
    // the NEXT ex factor (off the critical chain).
    #define TAKE_SCALE()                                                    \
    {                                                                       \
        int sb = lane0_bits(C01.x);                                         \
        int e  = (sb >> 23) & 0xff;                                         \
        kexp  += e - 127;                                                   \
        scl    = __int_as_float((254 - e) << 23);                           \
    }

    // ---- scan: PF-step chunks, x prefetch, renorm folded per chunk ----
    float xpf[PF];
    #pragma unroll
    for (int k = 0; k < PF; ++k) {
        int idx = base + dir * k;
        if (idx < 0) idx = 0;
        xpf[k] = sx[(size_t)idx * CT];
    }
    int k = 0;
    while (k + PF <= count) {
        float exk[PF];
        #pragma unroll
        for (int j = 0; j < PF; ++j) exk[j] = __expf(xpf[j]);
        #pragma unroll
        for (int j = 0; j < PF; ++j) {
            int idx = base + dir * (k + PF + j);
            if (idx < 0) idx = 0;
            xpf[j] = sx[(size_t)idx * CT];
        }
        TAKE_SCALE();
        exk[0] *= scl;
        STEP(exk[0]); STEP(exk[1]); STEP(exk[2]); STEP(exk[3]);
        STEP(exk[4]); STEP(exk[5]); STEP(exk[6]); STEP(exk[7]);
        k += PF;
    }
    if (k < count) {                       // remainder (<PF steps)
        TAKE_SCALE();
        int r = 0;
        for (; k < count; ++k, ++r) {
            float ex = __expf(xpf[r]);
            if (r == 0) ex *= scl;
            STEP(ex);
        }
    }
    // bwd epilogue: B_tm = E * C_{tm+1} (no exp(x) factor, just pending scale)
    if (w == 1 && len >= 2) {
        TAKE_SCALE();
        STEP(scl);
    }
    // final normalize (overflow guard for the combine product)
    {
        int sb = lane0_bits(C01.x);
        int e  = (sb >> 23) & 0xff;
        kexp  += e - 127;
        float s2 = __int_as_float((254 - e) << 23);
        C01 *= s2; C23 *= s2;
    }
    #undef STEP
    #undef TAKE_SCALE

    // extract own state st = comps[lane&3]
    float st;
    {
        const float o01 = (lane & 1) ? C01.y : C01.x;
        const float o23 = (lane & 1) ? C23.y : C23.x;
        st = (lane & 2) ? o23 : o01;
    }

    // ---- combine across waves ----
    if (w == 0) sA[lane] = (lane < CT) ? st : 0.0f;
    else        sB[lane] = (lane < CT) ? st : 0.0f;
    if (lane == 0) sLZ[w] = (float)kexp * 0.6931471805599453f;
    __syncthreads();

    // numerator: gold-path score, all 128 threads
    const int* trow = tags + (size_t)b * CS;
    float nsum = 0.0f;
    for (int t = tid; t < CS; t += 128) {
        if (t < len) {
            int tg = trow[t];
            nsum += srow[(size_t)t * CT + tg];
            if (t >= 1) nsum += sTrans[trow[t - 1] * CT + tg];
        }
    }
    #pragma unroll
    for (int off = 32; off; off >>= 1) nsum += __shfl_xor(nsum, off);
    if (lane == 0) sN[w] = nsum;

    float den = 0.0f;
    if (w == 0) {
        float vp = sA[lane] * sB[lane];
        #pragma unroll
        for (int off = 32; off; off >>= 1) vp += __shfl_xor(vp, off);
        den = sLZ[0] + sLZ[1] + __logf(vp);
    }
    __syncthreads();

    if (tid == 0) {
        float num = sN[0] + sN[1] + start_tr[trow[0]] + end_tr[trow[len - 1]];
        atomicAdd(out, (den - num) * (1.0f / CB));
    }
}

extern "C" void kernel_launch(void* const* d_in, const int* in_sizes, int n_in,
                              void* d_out, int out_size, void* d_ws, size_t ws_size,
                              hipStream_t stream) {
    const float* scores   = (const float*)d_in[0];
    const int*   tags     = (const int*)d_in[1];
    const int*   mask     = (const int*)d_in[2];
    const float* trans    = (const float*)d_in[3];
    const float* start_tr = (const float*)d_in[4];
    const float* end_tr   = (const float*)d_in[5];
    float* out = (float*)d_out;

    zero_out_kernel<<<1, 1, 0, stream>>>(out);
    crf_scan_kernel<<<CB, 128, 0, stream>>>(scores, tags, mask, trans,
                                            start_tr, end_tr, out);
}

// Round 7
// 294.682 us; speedup vs baseline: 1.0004x; 1.0004x over previous
//
#include <hip/hip_runtime.h>
#include <math.h>

#define CB 512
#define CS 1024
#define CT 50
#define PF 4   // x-prefetch depth / renorm cadence

typedef float v2f __attribute__((ext_vector_type(2)));

__global__ void zero_out_kernel(float* out) { out[0] = 0.0f; }

// Compiler-level fence only — same-wave DS ops complete in order on CDNA.
__device__ __forceinline__ void wave_fence() {
    __builtin_amdgcn_wave_barrier();
    asm volatile("" ::: "memory");
}

__device__ __forceinline__ int lane0_bits(float v) {
    return __builtin_amdgcn_readlane(__float_as_int(v), 0);
}

// quad_perm DPP (VALU pipe): 0xB1=xor1, 0x4E=xor2
template <int CTRL>
__device__ __forceinline__ float qperm(float v) {
    return __int_as_float(__builtin_amdgcn_update_dpp(
        0, __float_as_int(v), CTRL, 0xf, 0xf, false));
}

// One block = one sequence = ONE wave running BOTH chains (fwd + bwd) for ILP.
// __launch_bounds__(64,1): allow the full VGPR budget — R4's dual-chain attempt
// failed ONLY because the default heuristic capped VGPRs at ~88 and spilled
// (WRITE_SIZE 971 KB). Both E fragment sets must stay in registers.
__global__ __launch_bounds__(64, 1) void crf_scan_kernel(
    const float* __restrict__ scores,    // (B,S,T)
    const int*   __restrict__ tags,      // (B,S)
    const int*   __restrict__ mask,      // (B,S)
    const float* __restrict__ trans,     // (T,T)
    const float* __restrict__ start_tr,  // (T)
    const float* __restrict__ end_tr,    // (T)
    float* __restrict__ out)             // scalar
{
    const int b    = blockIdx.x;
    const int lane = threadIdx.x;
    const int g    = lane & 3;           // i-quarter this lane accumulates
    const int m    = lane >> 2;          // quad: owns states 4m..4m+3; lane owns state==lane
    const bool selb0 = (lane & 1) != 0;
    const bool selb1 = (lane & 2) != 0;

    __shared__ __attribute__((aligned(16))) float sTrans[CT * CT];
    __shared__ __attribute__((aligned(16))) float sPF[64];
    __shared__ __attribute__((aligned(16))) float sPR[64];

    for (int k = lane; k < CT * CT; k += 64) sTrans[k] = trans[k];
    __syncthreads();

    // E fragments for BOTH chains. Lane covers i in [16g,16g+16), states s=4m+c.
    // fwd: coeff(i,s)=exp(trans[i][s]); bwd: coeff(i,s)=exp(trans[s][i]).
    // Pads (i>=50 or s>=50) are exactly 0 so pad states stay 0 forever.
    v2f EF0[16], EF1[16], ER0[16], ER1[16];
    {
        const int i0 = 16 * g, s0 = 4 * m;
        #pragma unroll
        for (int kk = 0; kk < 16; ++kk) {
            const int i = i0 + kk;
            float eF[4] = {0.f,0.f,0.f,0.f}, eR[4] = {0.f,0.f,0.f,0.f};
            if (i < CT) {
                #pragma unroll
                for (int c = 0; c < 4; ++c) {
                    const int s = s0 + c;
                    if (s < CT) {
                        eF[c] = __expf(sTrans[i * CT + s]);
                        eR[c] = __expf(sTrans[s * CT + i]);
                    }
                }
            }
            EF0[kk] = (v2f){eF[0], eF[1]};  EF1[kk] = (v2f){eF[2], eF[3]};
            ER0[kk] = (v2f){eR[0], eR[1]};  ER1[kk] = (v2f){eR[2], eR[3]};
        }
    }

    // sequence length (prefix mask)
    const int* mrow = mask + (size_t)b * CS;
    int len = 0;
    for (int t = lane; t < CS; t += 64) len += mrow[t];
    #pragma unroll
    for (int off = 32; off; off >>= 1) len += __shfl_xor(len, off);

    const float* srow = scores + (size_t)b * CS * CT;
    const int xl      = (lane < CT) ? lane : 0;
    const float* sx   = srow + xl;

    const int tm     = (len - 1) >> 1;
    const int countF = tm;
    const int countB = (len >= 2) ? (len - 2 - tm) : 0;
    const int npair  = (countB < countF) ? countB : countF;  // countF-npair <= 1

    // linear-domain states; pad lanes exactly 0
    float stF = (lane < CT) ? __expf(start_tr[lane] + sx[0]) : 0.f;
    float stR = (lane < CT)
        ? ((len >= 2) ? __expf(end_tr[lane] + sx[(size_t)(len - 1) * CT])
                      : __expf(end_tr[lane]))
        : 0.f;
    int kexpF = 0, kexpR = 0;

    const float* sPFq = sPF + 16 * g;
    const float* sPRq = sPR + 16 * g;

    // Paired step: both chains share one fence pair; bodies interleave for ILP.
    #define STEP2(EXF, EXR)                                                 \
    {                                                                       \
        sPF[lane] = stF; sPR[lane] = stR;                                   \
        wave_fence();                                                       \
        const float4 f0 = *(const float4*)&sPFq[0];                         \
        const float4 f1 = *(const float4*)&sPFq[4];                         \
        const float4 f2 = *(const float4*)&sPFq[8];                         \
        const float4 f3 = *(const float4*)&sPFq[12];                        \
        const float4 r0 = *(const float4*)&sPRq[0];                         \
        const float4 r1 = *(const float4*)&sPRq[4];                         \
        const float4 r2 = *(const float4*)&sPRq[8];                         \
        const float4 r3 = *(const float4*)&sPRq[12];                        \
        wave_fence(); /* WAR: reads done before next iteration's write */   \
        float pf[16] = {f0.x,f0.y,f0.z,f0.w, f1.x,f1.y,f1.z,f1.w,           \
                        f2.x,f2.y,f2.z,f2.w, f3.x,f3.y,f3.z,f3.w};          \
        float pr[16] = {r0.x,r0.y,r0.z,r0.w, r1.x,r1.y,r1.z,r1.w,           \
                        r2.x,r2.y,r2.z,r2.w, r3.x,r3.y,r3.z,r3.w};          \
        v2f aF0 = {0.f,0.f}, aF1 = {0.f,0.f};                               \
        v2f aR0 = {0.f,0.f}, aR1 = {0.f,0.f};                               \
        _Pragma("unroll")                                                   \
        for (int kk = 0; kk < 16; ++kk) {                                   \
            const v2f tF = {pf[kk], pf[kk]};                                \
            const v2f tR = {pr[kk], pr[kk]};                                \
            aF0 = __builtin_elementwise_fma(tF, EF0[kk], aF0);              \
            aR0 = __builtin_elementwise_fma(tR, ER0[kk], aR0);              \
            aF1 = __builtin_elementwise_fma(tF, EF1[kk], aF1);              \
            aR1 = __builtin_elementwise_fma(tR, ER1[kk], aR1);              \
        }                                                                   \
        aF0.x += qperm<0xB1>(aF0.x); aF0.y += qperm<0xB1>(aF0.y);           \
        aR0.x += qperm<0xB1>(aR0.x); aR0.y += qperm<0xB1>(aR0.y);           \
        aF1.x += qperm<0xB1>(aF1.x); aF1.y += qperm<0xB1>(aF1.y);           \
        aR1.x += qperm<0xB1>(aR1.x); aR1.y += qperm<0xB1>(aR1.y);           \
        aF0.x += qperm<0x4E>(aF0.x); aF0.y += qperm<0x4E>(aF0.y);           \
        aR0.x += qperm<0x4E>(aR0.x); aR0.y += qperm<0x4E>(aR0.y);           \
        aF1.x += qperm<0x4E>(aF1.x); aF1.y += qperm<0x4E>(aF1.y);           \
        aR1.x += qperm<0x4E>(aR1.x); aR1.y += qperm<0x4E>(aR1.y);           \
        const float oF01 = selb0 ? aF0.y : aF0.x;                           \
        const float oF23 = selb0 ? aF1.y : aF1.x;                           \
        const float oR01 = selb0 ? aR0.y : aR0.x;                           \
        const float oR23 = selb0 ? aR1.y : aR1.x;                           \
        stF = (selb1 ? oF23 : oF01) * (EXF);                                \
        stR = (selb1 ? oR23 : oR01) * (EXR);                                \
    }

    // Single-chain steps for the (<=1-step) epilogues.
    #define STEP1(ST, SRC, Q, E0, E1, EX)                                   \
    {                                                                       \
        SRC[lane] = ST;                                                     \
        wave_fence();                                                       \
        const float4 p0 = *(const float4*)&Q[0];                            \
        const float4 p1 = *(const float4*)&Q[4];                            \
        const float4 p2 = *(const float4*)&Q[8];                            \
        const float4 p3 = *(const float4*)&Q[12];                           \
        wave_fence();                                                       \
        float pv[16] = {p0.x,p0.y,p0.z,p0.w, p1.x,p1.y,p1.z,p1.w,           \
                        p2.x,p2.y,p2.z,p2.w, p3.x,p3.y,p3.z,p3.w};          \
        v2f a0 = {0.f,0.f}, a1 = {0.f,0.f};                                 \
        _Pragma("unroll")                                                   \
        for (int kk = 0; kk < 16; ++kk) {                                   \
            const v2f t2 = {pv[kk], pv[kk]};                                \
            a0 = __builtin_elementwise_fma(t2, E0[kk], a0);                 \
            a1 = __builtin_elementwise_fma(t2, E1[kk], a1);                 \
        }                                                                   \
        a0.x += qperm<0xB1>(a0.x); a0.y += qperm<0xB1>(a0.y);               \
        a1.x += qperm<0xB1>(a1.x); a1.y += qperm<0xB1>(a1.y);               \
        a0.x += qperm<0x4E>(a0.x); a0.y += qperm<0x4E>(a0.y);               \
        a1.x += qperm<0x4E>(a1.x); a1.y += qperm<0x4E>(a1.y);               \
        const float o01 = selb0 ? a0.y : a0.x;                              \
        const float o23 = selb0 ? a1.y : a1.x;                              \
        ST = (selb1 ? o23 : o01) * (EX);                                    \
    }

    #define RENORM(ST, KE)                                                  \
    {                                                                       \
        int sb = lane0_bits(ST);                                            \
        int e  = (sb >> 23) & 0xff;                                         \
        KE    += e - 127;                                                   \
        ST    *= __int_as_float((254 - e) << 23);                           \
    }

    // ---- paired scan: PF-step chunks, dual x prefetch, renorm per chunk ----
    float xpf[PF], xpr[PF];
    #pragma unroll
    for (int k = 0; k < PF; ++k) {
        int iF = 1 + k;
        int iR = (len - 2) - k; if (iR < 0) iR = 0;
        xpf[k] = sx[(size_t)iF * CT];
        xpr[k] = sx[(size_t)iR * CT];
    }
    int k = 0;
    while (k + PF <= npair) {
        float exF[PF], exR[PF];
        #pragma unroll
        for (int j = 0; j < PF; ++j) { exF[j] = __expf(xpf[j]); exR[j] = __expf(xpr[j]); }
        #pragma unroll
        for (int j = 0; j < PF; ++j) {
            int iF = 1 + (k + PF + j);
            int iR = (len - 2) - (k + PF + j); if (iR < 0) iR = 0;
            xpf[j] = sx[(size_t)iF * CT];
            xpr[j] = sx[(size_t)iR * CT];
        }
        RENORM(stF, kexpF); RENORM(stR, kexpR);
        STEP2(exF[0], exR[0]); STEP2(exF[1], exR[1]);
        STEP2(exF[2], exR[2]); STEP2(exF[3], exR[3]);
        k += PF;
    }
    int r = 0;
    for (; k < npair; ++k, ++r) {
        float eF = __expf(xpf[r]), eR = __expf(xpr[r]);
        RENORM(stF, kexpF); RENORM(stR, kexpR);
        STEP2(eF, eR);
    }
    // fwd may have one extra step (countF = npair or npair+1)
    if (countF > npair) {
        float eF = __expf((r < PF) ? xpf[r] : sx[(size_t)(1 + npair) * CT]);
        RENORM(stF, kexpF);
        STEP1(stF, sPF, sPFq, EF0, EF1, eF);
    }
    // bwd epilogue: B_tm = E * C_{tm+1} (no exp(x) factor)
    if (len >= 2) {
        RENORM(stR, kexpR);
        STEP1(stR, sPR, sPRq, ER0, ER1, 1.0f);
    }
    RENORM(stF, kexpF); RENORM(stR, kexpR);
    #undef STEP2
    #undef STEP1
    #undef RENORM

    // ---- combine within the wave: den = (kexpF+kexpR)*ln2 + log sum_s aF[s]*B[s] ----
    float vp = (lane < CT) ? stF * stR : 0.0f;
    #pragma unroll
    for (int off = 32; off; off >>= 1) vp += __shfl_xor(vp, off);
    float den = (float)(kexpF + kexpR) * 0.6931471805599453f + __logf(vp);

    // ---- numerator: gold-path score ----
    const int* trow = tags + (size_t)b * CS;
    float nsum = 0.0f;
    for (int t = lane; t < CS; t += 64) {
        if (t < len) {
            int tg = trow[t];
            nsum += srow[(size_t)t * CT + tg];
            if (t >= 1) nsum += sTrans[trow[t - 1] * CT + tg];
        }
    }
    #pragma unroll
    for (int off = 32; off; off >>= 1) nsum += __shfl_xor(nsum, off);

    if (lane == 0) {
        nsum += start_tr[trow[0]] + end_tr[trow[len - 1]];
        atomicAdd(out, (den - nsum) * (1.0f / CB));
    }
}

extern "C" void kernel_launch(void* const* d_in, const int* in_sizes, int n_in,
                              void* d_out, int out_size, void* d_ws, size_t ws_size,
                              hipStream_t stream) {
    const float* scores   = (const float*)d_in[0];
    const int*   tags     = (const int*)d_in[1];
    const int*   mask     = (const int*)d_in[2];
    const float* trans    = (const float*)d_in[3];
    const float* start_tr = (const float*)d_in[4];
    const float* end_tr   = (const float*)d_in[5];
    float* out = (float*)d_out;

    zero_out_kernel<<<1, 1, 0, stream>>>(out);
    crf_scan_kernel<<<CB, 64, 0, stream>>>(scores, tags, mask, trans,
                                           start_tr, end_tr, out);
}